// Round 1
// baseline (39.591 us; speedup 1.0000x reference)
//
#include <hip/hip_runtime.h>

#define BATCH    8192
#define NNEIGH   64
#define FEAT     128
#define EMBED    64

// One block (256 threads = 4 waves) per batch row.
// Wave 0: score-diff + 64-lane bitonic top-k selection.
// All:   mean-pool 16 gathered feature rows + self feature load -> LDS cat[256].
// All:   cat[256] @ W[256,64], wave-partial dots reduced in LDS, ReLU, store.
__global__ __launch_bounds__(256) void intra_agg_kernel(
    const float* __restrict__ feat,    // [N_NODES, 128]
    const float* __restrict__ W,       // [256, 64]
    const int*   __restrict__ nodes,   // [B]
    const float* __restrict__ bscore,  // [B, 2]
    const float* __restrict__ nscore,  // [B, 64, 2]
    const int*   __restrict__ nids,    // [B, 64]
    const int*   __restrict__ ns_ptr,  // scalar num_sample (16)
    float*       __restrict__ out)     // [B*64] to_feats ++ [B*ns] samp_scores
{
    const int b    = blockIdx.x;
    const int tid  = threadIdx.x;
    const int lane = tid & 63;
    const int wave = tid >> 6;
    const int ns   = *ns_ptr;   // 16

    __shared__ int   s_sel[NNEIGH];      // selected neighbor ids (first ns used)
    __shared__ float s_cat[2 * FEAT];    // [self(128) | agg(128)]
    __shared__ float s_part[4][EMBED];   // per-wave partial dots

    if (wave == 0) {
        // ---- phase 1: score diffs + stable ascending bitonic sort ----
        const float center = bscore[b * 2];
        float d   = fabsf(center - nscore[(b * NNEIGH + lane) * 2]);
        int   idx = lane;
        #pragma unroll
        for (int k = 2; k <= 64; k <<= 1) {
            #pragma unroll
            for (int j = k >> 1; j > 0; j >>= 1) {
                const float od = __shfl_xor(d, j);
                const int   oi = __shfl_xor(idx, j);
                const bool up    = ((lane & k) == 0);
                const bool lower = ((lane & j) == 0);
                // lexicographic (value, index) => matches jax stable top_k
                const bool oless = (od < d) || (od == d && oi < idx);
                const bool take  = (lower == up) ? oless : !oless;
                if (take) { d = od; idx = oi; }
            }
        }
        if (lane < ns) {
            out[(size_t)BATCH * EMBED + (size_t)b * ns + lane] = d; // ascending diffs
            s_sel[lane] = nids[b * NNEIGH + idx];
        }
    }
    __syncthreads();

    // ---- phase 2: build cat = [self_feats | mean of selected neigh feats] ----
    if (tid < FEAT) {
        float sum = 0.f;
        for (int j = 0; j < ns; ++j) {
            sum += feat[(size_t)s_sel[j] * FEAT + tid];   // coalesced 512B per row
        }
        s_cat[FEAT + tid] = sum * (1.0f / (float)ns);
    } else {
        const int dck = tid - FEAT;
        s_cat[dck] = feat[(size_t)nodes[b] * FEAT + dck];
    }
    __syncthreads();

    // ---- phase 3: out[e] = relu(sum_k cat[k] * W[k][e]) ----
    {
        const int e  = lane;
        const int k0 = wave * 64;
        float acc = 0.f;
        #pragma unroll
        for (int k = 0; k < 64; ++k) {
            acc += s_cat[k0 + k] * W[(k0 + k) * EMBED + e];  // lanes coalesced over e
        }
        s_part[wave][e] = acc;
    }
    __syncthreads();

    if (wave == 0) {
        const float v = s_part[0][lane] + s_part[1][lane]
                      + s_part[2][lane] + s_part[3][lane];
        out[(size_t)b * EMBED + lane] = fmaxf(v, 0.f);
    }
}

extern "C" void kernel_launch(void* const* d_in, const int* in_sizes, int n_in,
                              void* d_out, int out_size, void* d_ws, size_t ws_size,
                              hipStream_t stream) {
    const float* feat   = (const float*)d_in[0];
    const float* W      = (const float*)d_in[1];
    const int*   nodes  = (const int*)d_in[2];
    const float* bscore = (const float*)d_in[3];
    const float* nscore = (const float*)d_in[4];
    const int*   nids   = (const int*)d_in[5];
    const int*   nsamp  = (const int*)d_in[6];
    float* out = (float*)d_out;

    intra_agg_kernel<<<BATCH, 256, 0, stream>>>(feat, W, nodes, bscore, nscore,
                                                nids, nsamp, out);
}

// Round 2
// 33.553 us; speedup vs baseline: 1.1799x; 1.1799x over previous
//
#include <hip/hip_runtime.h>

#define BATCH   8192
#define NNEIGH  64
#define FEAT    128
#define EMBED   64
#define ROWS    16          // batch rows per block
#define CATP    260         // padded cat row stride (floats): 260%32=4 -> bank spread
#define EPAD    68          // padded s_part stride

// 256 threads = 4 waves per block, 16 rows per block.
// P1: each wave bitonic-sorts 4 rows (prefetched, independent chains).
// P2: 8 groups x 32 threads; group g aggregates rows 2g,2g+1 with unrolled
//     float4 gathers (17 independent 16B loads/thread).
// P3: split-k matmul: wave = k-chunk of 64; thread = (4 rows x 4 cols) tile;
//     W element shared across 4 rows in registers. LDS partial reduce + ReLU.
__global__ __launch_bounds__(256, 2) void intra_agg_kernel(
    const float* __restrict__ feat,    // [N_NODES, 128]
    const float* __restrict__ W,       // [256, 64]
    const int*   __restrict__ nodes,   // [B]
    const float* __restrict__ bscore,  // [B, 2]
    const float* __restrict__ nscore,  // [B, 64, 2]
    const int*   __restrict__ nids,    // [B, 64]
    const int*   __restrict__ ns_ptr,  // scalar num_sample (16)
    float*       __restrict__ out)     // [B*64] to_feats ++ [B*ns] samp_scores
{
    const int b0   = blockIdx.x * ROWS;
    const int tid  = threadIdx.x;
    const int lane = tid & 63;
    const int wave = tid >> 6;
    const int ns   = *ns_ptr;

    __shared__ int   s_sel[ROWS][NNEIGH];
    __shared__ float s_cat[ROWS * CATP];
    __shared__ float s_part[4][ROWS][EPAD];

    // ---------------- phase 1: sort (4 rows per wave, prefetched) -----------
    float d[4];
    int   idx[4];
    #pragma unroll
    for (int i = 0; i < 4; ++i) {
        const int row = b0 + wave * 4 + i;
        const float  ctr = bscore[row * 2];
        const float2 sc  = *(const float2*)&nscore[(size_t)(row * NNEIGH + lane) * 2];
        d[i]   = fabsf(ctr - sc.x);
        idx[i] = lane;
    }
    #pragma unroll
    for (int i = 0; i < 4; ++i) {
        #pragma unroll
        for (int k = 2; k <= 64; k <<= 1) {
            #pragma unroll
            for (int j = k >> 1; j > 0; j >>= 1) {
                const float od = __shfl_xor(d[i], j);
                const int   oi = __shfl_xor(idx[i], j);
                const bool up    = ((lane & k) == 0);
                const bool lower = ((lane & j) == 0);
                // lexicographic (value, index) => jax stable top_k tie-break
                const bool oless = (od < d[i]) || (od == d[i] && oi < idx[i]);
                if ((lower == up) ? oless : !oless) { d[i] = od; idx[i] = oi; }
            }
        }
    }
    #pragma unroll
    for (int i = 0; i < 4; ++i) {
        const int r   = wave * 4 + i;
        const int row = b0 + r;
        if (lane < ns) {
            out[(size_t)BATCH * EMBED + (size_t)row * ns + lane] = d[i];
            s_sel[r][lane] = nids[row * NNEIGH + idx[i]];
        }
    }
    __syncthreads();

    // ---------------- phase 2: gather + mean + self -------------------------
    {
        const int g = tid >> 5;       // 0..7
        const int c = tid & 31;       // float4 chunk within 128-wide row
        const float inv_ns = 1.0f / (float)ns;
        #pragma unroll
        for (int rr = 0; rr < 2; ++rr) {
            const int r   = g * 2 + rr;
            const int row = b0 + r;
            float4 a = make_float4(0.f, 0.f, 0.f, 0.f);
            if (ns == 16) {
                #pragma unroll
                for (int j = 0; j < 16; ++j) {
                    const float4 v = *(const float4*)&feat[(size_t)s_sel[r][j] * FEAT + c * 4];
                    a.x += v.x; a.y += v.y; a.z += v.z; a.w += v.w;
                }
            } else {
                for (int j = 0; j < ns; ++j) {
                    const float4 v = *(const float4*)&feat[(size_t)s_sel[r][j] * FEAT + c * 4];
                    a.x += v.x; a.y += v.y; a.z += v.z; a.w += v.w;
                }
            }
            const float4 sf = *(const float4*)&feat[(size_t)nodes[row] * FEAT + c * 4];
            *(float4*)&s_cat[r * CATP + c * 4] = sf;
            a.x *= inv_ns; a.y *= inv_ns; a.z *= inv_ns; a.w *= inv_ns;
            *(float4*)&s_cat[r * CATP + FEAT + c * 4] = a;
        }
    }
    __syncthreads();

    // ---------------- phase 3: split-k matmul, 4x4 register tile ------------
    {
        const int q  = tid & 15;          // 4-col group of W/out
        const int rq = (tid >> 4) & 3;    // 4-row quad
        const int ks = wave;              // k-chunk of 64
        const int k0 = ks * 64;

        float4 acc[4];
        #pragma unroll
        for (int r = 0; r < 4; ++r) acc[r] = make_float4(0.f, 0.f, 0.f, 0.f);

        #pragma unroll 4
        for (int kk = 0; kk < 64; kk += 4) {
            const int k = k0 + kk;
            float4 cv[4];
            #pragma unroll
            for (int r = 0; r < 4; ++r)
                cv[r] = *(const float4*)&s_cat[(rq * 4 + r) * CATP + k];
            #pragma unroll
            for (int t = 0; t < 4; ++t) {
                const float4 w4 = *(const float4*)&W[(size_t)(k + t) * EMBED + q * 4];
                #pragma unroll
                for (int r = 0; r < 4; ++r) {
                    const float cf = (t == 0) ? cv[r].x : (t == 1) ? cv[r].y
                                   : (t == 2) ? cv[r].z : cv[r].w;
                    acc[r].x += cf * w4.x; acc[r].y += cf * w4.y;
                    acc[r].z += cf * w4.z; acc[r].w += cf * w4.w;
                }
            }
        }
        #pragma unroll
        for (int r = 0; r < 4; ++r)
            *(float4*)&s_part[ks][rq * 4 + r][q * 4] = acc[r];
    }
    __syncthreads();

    // ---------------- phase 4: reduce k-chunks, ReLU, store ------------------
    {
        const int r2 = tid >> 4;          // 0..15
        const int q  = tid & 15;
        float4 o = make_float4(0.f, 0.f, 0.f, 0.f);
        #pragma unroll
        for (int p = 0; p < 4; ++p) {
            const float4 v = *(const float4*)&s_part[p][r2][q * 4];
            o.x += v.x; o.y += v.y; o.z += v.z; o.w += v.w;
        }
        o.x = fmaxf(o.x, 0.f); o.y = fmaxf(o.y, 0.f);
        o.z = fmaxf(o.z, 0.f); o.w = fmaxf(o.w, 0.f);
        *(float4*)&out[(size_t)(b0 + r2) * EMBED + q * 4] = o;
    }
}

extern "C" void kernel_launch(void* const* d_in, const int* in_sizes, int n_in,
                              void* d_out, int out_size, void* d_ws, size_t ws_size,
                              hipStream_t stream) {
    const float* feat   = (const float*)d_in[0];
    const float* W      = (const float*)d_in[1];
    const int*   nodes  = (const int*)d_in[2];
    const float* bscore = (const float*)d_in[3];
    const float* nscore = (const float*)d_in[4];
    const int*   nids   = (const int*)d_in[5];
    const int*   nsamp  = (const int*)d_in[6];
    float* out = (float*)d_out;

    intra_agg_kernel<<<BATCH / ROWS, 256, 0, stream>>>(feat, W, nodes, bscore,
                                                       nscore, nids, nsamp, out);
}

// Round 3
// 24.274 us; speedup vs baseline: 1.6310x; 1.3823x over previous
//
#include <hip/hip_runtime.h>

#define BATCH   8192
#define NNEIGH  64
#define FEAT    128
#define EMBED   64
#define ROWS    8           // batch rows per block
#define CATP    260         // padded cat row stride (floats), 260*4B = 65*16B (b128-aligned)
#define EPAD    68          // padded s_part stride (68*4B = 17*16B)
#define KCHUNKS 8           // split-k chunks of 32

// 256 threads = 4 waves per block, 8 rows per block, grid = 1024 (4 blocks/CU).
// P1: each wave bitonic-sorts 2 rows (independent shuffle chains).
// P2: 32-thread group per row; 17 unrolled float4 gathers per thread.
// P3: split-k matmul: thread = (col-quad q, row-quad rq, k-chunk ks);
//     W float4 shared across 4 rows in registers (2x W replication per block).
// P4: reduce 8 k-chunks in LDS, ReLU, store.
__global__ __launch_bounds__(256, 4) void intra_agg_kernel(
    const float* __restrict__ feat,    // [N_NODES, 128]
    const float* __restrict__ W,       // [256, 64]
    const int*   __restrict__ nodes,   // [B]
    const float* __restrict__ bscore,  // [B, 2]
    const float* __restrict__ nscore,  // [B, 64, 2]
    const int*   __restrict__ nids,    // [B, 64]
    const int*   __restrict__ ns_ptr,  // scalar num_sample (16)
    float*       __restrict__ out)     // [B*64] to_feats ++ [B*ns] samp_scores
{
    const int b0   = blockIdx.x * ROWS;
    const int tid  = threadIdx.x;
    const int lane = tid & 63;
    const int wave = tid >> 6;
    const int ns   = *ns_ptr;

    __shared__ int   s_sel[ROWS][NNEIGH];
    __shared__ float s_cat[ROWS * CATP];
    __shared__ float s_part[KCHUNKS][ROWS][EPAD];

    // ---------------- phase 1: sort (2 rows per wave) -----------------------
    {
        float d[2];
        int   idx[2];
        #pragma unroll
        for (int i = 0; i < 2; ++i) {
            const int row = b0 + wave * 2 + i;
            const float  ctr = bscore[row * 2];
            const float2 sc  = *(const float2*)&nscore[(size_t)(row * NNEIGH + lane) * 2];
            d[i]   = fabsf(ctr - sc.x);
            idx[i] = lane;
        }
        #pragma unroll
        for (int i = 0; i < 2; ++i) {
            #pragma unroll
            for (int k = 2; k <= 64; k <<= 1) {
                #pragma unroll
                for (int j = k >> 1; j > 0; j >>= 1) {
                    const float od = __shfl_xor(d[i], j);
                    const int   oi = __shfl_xor(idx[i], j);
                    const bool up    = ((lane & k) == 0);
                    const bool lower = ((lane & j) == 0);
                    // lexicographic (value, index) => jax stable top_k tie-break
                    const bool oless = (od < d[i]) || (od == d[i] && oi < idx[i]);
                    if ((lower == up) ? oless : !oless) { d[i] = od; idx[i] = oi; }
                }
            }
        }
        #pragma unroll
        for (int i = 0; i < 2; ++i) {
            const int r   = wave * 2 + i;
            const int row = b0 + r;
            if (lane < ns) {
                out[(size_t)BATCH * EMBED + (size_t)row * ns + lane] = d[i];
                s_sel[r][lane] = nids[row * NNEIGH + idx[i]];
            }
        }
    }
    __syncthreads();

    // ---------------- phase 2: gather + mean + self -------------------------
    {
        const int r   = tid >> 5;      // row within block (0..7)
        const int c   = tid & 31;      // float4 chunk within 128-wide row
        const int row = b0 + r;
        const float inv_ns = 1.0f / (float)ns;
        float4 a = make_float4(0.f, 0.f, 0.f, 0.f);
        if (ns == 16) {
            #pragma unroll
            for (int j = 0; j < 16; ++j) {
                const float4 v = *(const float4*)&feat[(size_t)s_sel[r][j] * FEAT + c * 4];
                a.x += v.x; a.y += v.y; a.z += v.z; a.w += v.w;
            }
        } else {
            for (int j = 0; j < ns; ++j) {
                const float4 v = *(const float4*)&feat[(size_t)s_sel[r][j] * FEAT + c * 4];
                a.x += v.x; a.y += v.y; a.z += v.z; a.w += v.w;
            }
        }
        const float4 sf = *(const float4*)&feat[(size_t)nodes[row] * FEAT + c * 4];
        *(float4*)&s_cat[r * CATP + c * 4] = sf;
        a.x *= inv_ns; a.y *= inv_ns; a.z *= inv_ns; a.w *= inv_ns;
        *(float4*)&s_cat[r * CATP + FEAT + c * 4] = a;
    }
    __syncthreads();

    // ---------------- phase 3: split-k matmul, (4 rows x 4 cols) tile -------
    {
        const int q  = tid & 15;          // 4-col group of W/out
        const int rq = (tid >> 4) & 1;    // row-quad: rows rq*4 .. rq*4+3
        const int ks = tid >> 5;          // k-chunk of 32 (0..7)
        const int k0 = ks * 32;

        float4 acc[4];
        #pragma unroll
        for (int r = 0; r < 4; ++r) acc[r] = make_float4(0.f, 0.f, 0.f, 0.f);

        #pragma unroll
        for (int kk = 0; kk < 32; kk += 4) {
            const int k = k0 + kk;
            float4 cv[4];
            #pragma unroll
            for (int r = 0; r < 4; ++r)
                cv[r] = *(const float4*)&s_cat[(rq * 4 + r) * CATP + k];
            #pragma unroll
            for (int t = 0; t < 4; ++t) {
                const float4 w4 = *(const float4*)&W[(size_t)(k + t) * EMBED + q * 4];
                #pragma unroll
                for (int r = 0; r < 4; ++r) {
                    const float cf = (t == 0) ? cv[r].x : (t == 1) ? cv[r].y
                                   : (t == 2) ? cv[r].z : cv[r].w;
                    acc[r].x += cf * w4.x; acc[r].y += cf * w4.y;
                    acc[r].z += cf * w4.z; acc[r].w += cf * w4.w;
                }
            }
        }
        #pragma unroll
        for (int r = 0; r < 4; ++r)
            *(float4*)&s_part[ks][rq * 4 + r][q * 4] = acc[r];
    }
    __syncthreads();

    // ---------------- phase 4: reduce k-chunks, ReLU, store ------------------
    if (tid < ROWS * 16) {
        const int r2 = tid >> 4;          // 0..7
        const int q  = tid & 15;
        float4 o = make_float4(0.f, 0.f, 0.f, 0.f);
        #pragma unroll
        for (int p = 0; p < KCHUNKS; ++p) {
            const float4 v = *(const float4*)&s_part[p][r2][q * 4];
            o.x += v.x; o.y += v.y; o.z += v.z; o.w += v.w;
        }
        o.x = fmaxf(o.x, 0.f); o.y = fmaxf(o.y, 0.f);
        o.z = fmaxf(o.z, 0.f); o.w = fmaxf(o.w, 0.f);
        *(float4*)&out[(size_t)(b0 + r2) * EMBED + q * 4] = o;
    }
}

extern "C" void kernel_launch(void* const* d_in, const int* in_sizes, int n_in,
                              void* d_out, int out_size, void* d_ws, size_t ws_size,
                              hipStream_t stream) {
    const float* feat   = (const float*)d_in[0];
    const float* W      = (const float*)d_in[1];
    const int*   nodes  = (const int*)d_in[2];
    const float* bscore = (const float*)d_in[3];
    const float* nscore = (const float*)d_in[4];
    const int*   nids   = (const int*)d_in[5];
    const int*   nsamp  = (const int*)d_in[6];
    float* out = (float*)d_out;

    intra_agg_kernel<<<BATCH / ROWS, 256, 0, stream>>>(feat, W, nodes, bscore,
                                                       nscore, nids, nsamp, out);
}